// Round 1
// baseline (1287.235 us; speedup 1.0000x reference)
//
#include <hip/hip_runtime.h>

// Segment-mean over sorted segment ids.
// feats: [N, 128] fp32 row-major; ids: [N] sorted int32; out: [S, 128] fp32.
// One block per segment: binary-search the contiguous row range, float4
// cooperative sum (8 rows per iteration across 256 threads), LDS reduce,
// scale by 1/count, vector store. Empty segments write 0.

#define FEAT_D 128           // floats per row
#define ROW_F4 32            // float4s per row
#define BLOCK 256            // 8 row-groups of 32 lanes

__global__ __launch_bounds__(BLOCK) void seg_mean_kernel(
    const float* __restrict__ feats,
    const int* __restrict__ ids,
    float* __restrict__ out,
    int N)
{
    const int s   = blockIdx.x;
    const int tid = threadIdx.x;

    __shared__ int bounds[2];
    if (tid < 2) {
        // lower_bound of (s + tid) in ids[0..N)
        int target = s + tid;
        int lo = 0, hi = N;
        while (lo < hi) {
            int mid = (lo + hi) >> 1;
            if (ids[mid] < target) lo = mid + 1; else hi = mid;
        }
        bounds[tid] = lo;
    }
    __syncthreads();
    const int start = bounds[0];
    const int end   = bounds[1];
    const int count = end - start;

    // group g handles rows start+g, start+g+8, ...; lane c handles float4 c
    const int g = tid >> 5;        // 0..7
    const int c = tid & 31;        // 0..31

    float4 acc = make_float4(0.f, 0.f, 0.f, 0.f);
    const float4* __restrict__ f4 = reinterpret_cast<const float4*>(feats);
    for (int r = start + g; r < end; r += 8) {
        float4 v = f4[(size_t)r * ROW_F4 + c];
        acc.x += v.x; acc.y += v.y; acc.z += v.z; acc.w += v.w;
    }

    __shared__ float4 smem[BLOCK];
    smem[tid] = acc;
    __syncthreads();

    if (tid < 32) {
        float4 t = smem[tid];
#pragma unroll
        for (int k = 1; k < 8; ++k) {
            float4 v = smem[tid + 32 * k];
            t.x += v.x; t.y += v.y; t.z += v.z; t.w += v.w;
        }
        const float inv = 1.0f / (float)(count > 0 ? count : 1);
        t.x *= inv; t.y *= inv; t.z *= inv; t.w *= inv;
        reinterpret_cast<float4*>(out)[(size_t)s * ROW_F4 + tid] = t;
    }
}

extern "C" void kernel_launch(void* const* d_in, const int* in_sizes, int n_in,
                              void* d_out, int out_size, void* d_ws, size_t ws_size,
                              hipStream_t stream) {
    const float* feats = (const float*)d_in[0];
    const int*   ids   = (const int*)d_in[1];
    // d_in[2] is num_segments (device scalar) — derive S from out_size instead.
    float* out = (float*)d_out;

    const int N = in_sizes[1];            // number of rows (== in_sizes[0] / 128)
    const int S = out_size / FEAT_D;      // number of segments

    seg_mean_kernel<<<S, BLOCK, 0, stream>>>(feats, ids, out, N);
}